// Round 10
// baseline (213.369 us; speedup 1.0000x reference)
//
#include <hip/hip_runtime.h>

// Causal SDPA, B=16, N=4096, DK=DV=64, fp32 in/out. R19 = R18 with the
// per-wave dependency chain BROKEN by a one-tile PV lag:
//   iteration kt:  PV(u_prev, V(kt-1))  ||  QK(kt) -> st   (independent MFMA
//   groups, interleavable)  then softmax(st) -> u, l  (latency ages a full
//   iteration before PV consumes it).
// R18 post-mortem: 3-deep prefetch null (85.8 vs 85.6) -- memory exonerated
// at every level across R11..R18. Surviving difference R11 (71.6, 81% pipe
// busy) vs R13+ (86, 52%): R11 had ~12 independent MFMA chains/iter; R13+'s
// QK is 4 serial mfma_32x32x16 into ONE accumulator -> lockstep waves all
// stall at the same chain point. This round adds cross-group ILP without
// adding MFMAs.
// Also: ones-MFMA row-sum replaced by per-lane f32 tree-add of pex (+1 VGPR
// vs +16, -2 MFMAs/iter); row sums transposed once per item via a 2 KB LDS
// lsum in the existing reduction epilogue.
// Carried from R18: 128-row q-tiles (8 waves, wq 0..3 x wk 0..1), 4-slot
// 64 KB circular staging (lead 2 tiles, vmcnt ladder 4/2/0), K-image row
// bit2<->3 permutation (QK C-reg order == PV A-k order), V 16B-granule
// image, exact static split-K schedule, cross-wk LDS reduction, exp2 softmax.

#define N_SEQ 4096
#define DIM   64

typedef __bf16  bf16x8 __attribute__((ext_vector_type(8)));
typedef unsigned short u16x8 __attribute__((ext_vector_type(8)));
typedef float   f32x4  __attribute__((ext_vector_type(4)));
typedef float   f32x16 __attribute__((ext_vector_type(16)));

static __device__ __forceinline__ unsigned short f2bf(float f) {
    unsigned int u = __float_as_uint(f);
    u += 0x7FFFu + ((u >> 16) & 1u);   // RNE
    return (unsigned short)(u >> 16);
}

static __device__ __forceinline__ unsigned int pk2bf(float a, float b) {
#if defined(__HIP_DEVICE_COMPILE__) && __has_builtin(__builtin_amdgcn_cvt_pk_bf16_f32)
    typedef __bf16 bf16x2_t __attribute__((ext_vector_type(2)));
    bf16x2_t r = __builtin_amdgcn_cvt_pk_bf16_f32(a, b);
    return __builtin_bit_cast(unsigned int, r);
#else
    return (unsigned int)f2bf(a) | ((unsigned int)f2bf(b) << 16);
#endif
}

static __device__ __forceinline__ float fexp2(float x) {
#if defined(__HIP_DEVICE_COMPILE__) && __has_builtin(__builtin_amdgcn_exp2f)
    return __builtin_amdgcn_exp2f(x);
#else
    return exp2f(x);
#endif
}

static __device__ __forceinline__ bf16x8 ld_frag(const void* p) {
    u16x8 u = *reinterpret_cast<const u16x8*>(p);  // ds_read_b128
    return __builtin_bit_cast(bf16x8, u);
}

// 32x32x16 bf16 MFMA: A,B = 8 bf16/lane (4 VGPR), C/D = 16 f32/lane.
static __device__ __forceinline__ f32x16 mfma32(bf16x8 a, bf16x8 b, f32x16 c) {
#if defined(__HIP_DEVICE_COMPILE__)
#if __has_builtin(__builtin_amdgcn_mfma_f32_32x32x16_bf16)
    return __builtin_amdgcn_mfma_f32_32x32x16_bf16(a, b, c, 0, 0, 0);
#else
    f32x16 d;
    asm volatile("v_mfma_f32_32x32x16_bf16 %0, %1, %2, %3"
                 : "=v"(d) : "v"(a), "v"(b), "v"(c));
    return d;
#endif
#else
    (void)a; (void)b;
    return c;
#endif
}

static __device__ __forceinline__ void gl_lds16(const unsigned short* g, unsigned short* l) {
#if defined(__HIP_DEVICE_COMPILE__)
    __builtin_amdgcn_global_load_lds(
        (const __attribute__((address_space(1))) unsigned int*)(g),
        (__attribute__((address_space(3))) unsigned int*)(l), 16, 0, 0);
#else
    (void)g; (void)l;
#endif
}

// ---- fused pre-pass: z=0: K image (rows bit2<->3 permuted); z=1: V^T image ----
__global__ __launch_bounds__(256)
void prep_kv(const float* __restrict__ K, const float* __restrict__ V,
             unsigned short* __restrict__ wsK, unsigned short* __restrict__ wsV) {
    const int b = blockIdx.y, t = blockIdx.x;
    if (blockIdx.z == 0) {
        const float* src = K + ((size_t)b * N_SEQ + t * 64) * DIM;
        unsigned short* dst = wsK + ((size_t)(b * 64 + t)) * 4096;
        #pragma unroll
        for (int ph = 0; ph < 2; ++ph) {
            const int gidx = threadIdx.x + ph * 256;
            const int r = gidx >> 3, g = gidx & 7;     // r = actual kpos, g = dk octet
            const float* p = src + r * DIM + g * 8;
            f32x4 f0 = *reinterpret_cast<const f32x4*>(p);
            f32x4 f1 = *reinterpret_cast<const f32x4*>(p + 4);
            uint4 w;
            w.x = pk2bf(f0[0], f0[1]); w.y = pk2bf(f0[2], f0[3]);
            w.z = pk2bf(f1[0], f1[1]); w.w = pk2bf(f1[2], f1[3]);
            // image row = r with bits 2,3 swapped (involution)
            const int rp = (r & 51) | ((r & 4) << 1) | ((r & 8) >> 1);
            *reinterpret_cast<uint4*>(&dst[(rp * 8 + (g ^ (rp & 7))) * 8]) = w;
        }
    } else {
        // V^T image: row dv (64 kpos bf16 = 128 B = 8 granules of 8 bf16).
        // Granule (c ^ (dv&7)) of row dv holds kpos octet c*8..c*8+7.
        const int dv = threadIdx.x & 63;
        const int g0 = threadIdx.x >> 6;               // 0..3
        const float* src = V + ((size_t)b * N_SEQ + t * 64) * DIM + dv;
        unsigned short* dst = wsV + ((size_t)(b * 64 + t)) * 4096 + dv * 64;
        #pragma unroll
        for (int ph = 0; ph < 2; ++ph) {
            const int c = g0 * 2 + ph;                 // content octet 0..7
            float p[8];
            #pragma unroll
            for (int e = 0; e < 8; ++e)
                p[e] = src[(size_t)(c * 8 + e) * DIM]; // coalesced over dv
            uint4 w;
            w.x = pk2bf(p[0], p[1]); w.y = pk2bf(p[2], p[3]);
            w.z = pk2bf(p[4], p[5]); w.w = pk2bf(p[6], p[7]);
            *reinterpret_cast<uint4*>(&dst[(c ^ (dv & 7)) * 8]) = w;
        }
    }
}

// ---- main: flash attention, 128-row q-tiles, PV-lag software pipeline ----
__global__ __launch_bounds__(512, 1)
void attn_fwd(const float* __restrict__ Q, const unsigned short* __restrict__ wsK,
              const unsigned short* __restrict__ wsV, float* __restrict__ O,
              float* __restrict__ wsO, float* __restrict__ wsL) {
    // smem (u16): K slots [0,16384) = 4 x 4096, V slots [16384,32768) = 4 x 4096.
    // Epilogue aliases: red = f32[0..8191] (32 KB), lsum = 512 f32 after.
    __shared__ unsigned short smem[32768];

    const int tid  = threadIdx.x;
    const int wave = tid >> 6;                 // 0..7
    const int lane = tid & 63;
    const int l31  = lane & 31;
    const int h    = lane >> 5;                // half-wave
    const int l7   = lane & 7;
    const int wq   = wave & 3;                 // q quarter (rows wq*32..+32)
    const int wk   = wave >> 2;                // kpos-half (kpos wk*32..+32)

    const int L    = (int)blockIdx.x;
    const int r    = L & 7;                    // XCD queue (batches {2r,2r+1})
    const int w    = L >> 3;                   // worker 0..63
    const int role = w & 1;                    // 0=A, 1=B
    const int bsel = (w >> 1) & 1;
    const int j    = w >> 2;                   // pair index 0..15
    const int b    = r * 2 + bsel;
    const int Tq   = 31 - j;                   // deep q-tile (depth 64-2j k-tiles)

    // item list (<=2): {tile, kt0, kt1, partial(half)}; depths: 2j+2 / 64-2j
    int it_tile[2], it_k0[2], it_k1[2], it_half[2], n_items;
    if (role == 0) {                   // A: shallow tile full + deep head
        it_tile[0] = j;   it_k0[0] = 0;          it_k1[0] = 2 * j + 2;  it_half[0] = -1;
        it_tile[1] = Tq;  it_k0[1] = 0;          it_k1[1] = 31 - 2 * j; it_half[1] = 0;
        n_items = 2;                   // (2j+2)+(31-2j) = 33
    } else {                           // B: deep tail (33 k-tiles, incl. diagonal)
        it_tile[0] = Tq;  it_k0[0] = 31 - 2 * j; it_k1[0] = 64 - 2 * j; it_half[0] = 1;
        n_items = 1;
    }

    // loop-invariant LDS byte addresses (within an 8 KB K / V slot)
    int kaddr[4];   // [s]: K A-frag, image row wk*32+l31, granule (s*2+h)^l7
    #pragma unroll
    for (int s = 0; s < 4; ++s)
        kaddr[s] = (wk * 32 + l31) * 128 + (((s * 2 + h) ^ l7) * 16);
    int vbase[2];   // [t]: V B-frag, row l31 (+dvt*4096B), granule (wk*4+t*2+h)^l7
    #pragma unroll
    for (int t = 0; t < 2; ++t)
        vbase[t] = l31 * 128 + (((wk * 4 + t * 2 + h) ^ l7) * 16);

    const int dma_off = wave * 512 + lane * 8;        // u16; 16B/lane, 1KB/wave
    const float QS = 0.125f * 1.44269504f;            // scale * log2(e)

    const unsigned short* kt_src = wsK + (size_t)b * 64 * 4096;
    const unsigned short* vt_src = wsV + (size_t)b * 64 * 4096;

    for (int it = 0; it < n_items; ++it) {
        const int tt    = it_tile[it];
        const int kt0   = it_k0[it];
        const int kt1   = it_k1[it];
        const int half  = it_half[it];
        const int i0    = tt * 128;            // q-tile base row
        const int tdiag = 2 * tt;              // first k-tile needing mask

        __syncthreads();                 // LDS free from previous item

        f32x16 o_acc[2] = {};  // [dvt]: D[q][dv], col dv=dvt*32+l31, rows q-pattern
        unsigned int u[8];     // P(kt-1) as bf16 A-fragments (carried one tile)
        float l_lane = 0.0f;   // per-lane row-sum partial (q=wq*32+l31; this h,wk)

        if (kt0 < kt1) {
            // Q fragments (B-operand): lane = q row i0+wq*32+l31, k = s*16+h*8+jj
            u16x8 qb[4];
            const float* qptr = Q + ((size_t)b * N_SEQ + i0 + wq * 32 + l31) * DIM;
            #pragma unroll
            for (int s = 0; s < 4; ++s) {
                const float* p = qptr + s * 16 + h * 8;
                f32x4 f0 = *reinterpret_cast<const f32x4*>(p);
                f32x4 f1 = *reinterpret_cast<const f32x4*>(p + 4);
                #pragma unroll
                for (int jj = 0; jj < 4; ++jj) {
                    qb[s][jj]     = f2bf(f0[jj] * QS);
                    qb[s][4 + jj] = f2bf(f1[jj] * QS);
                }
            }

            auto dma = [&](int kt) {            // 16 KB k-tile, slot kt&3
                const int sl = (kt & 3) * 4096;
                gl_lds16(kt_src + (size_t)kt * 4096 + dma_off, &smem[sl + dma_off]);
                gl_lds16(vt_src + (size_t)kt * 4096 + dma_off, &smem[16384 + sl + dma_off]);
            };

            // PV: O += P(u) * V-tile (reads V slot of the LAGGED tile)
            auto pv = [&](const unsigned short* vb) {
                #pragma unroll
                for (int t = 0; t < 2; ++t) {
                    uint4 aw = make_uint4(u[4 * t], u[4 * t + 1], u[4 * t + 2], u[4 * t + 3]);
                    bf16x8 pa = __builtin_bit_cast(bf16x8, aw);
                    #pragma unroll
                    for (int dvt = 0; dvt < 2; ++dvt) {
                        bf16x8 bv = ld_frag((const char*)vb + vbase[t] + dvt * 4096);
                        o_acc[dvt] = mfma32(pa, bv, o_acc[dvt]);
                    }
                }
            };

            // QK + softmax: st = K*Q^T quadrant; u = bf16(exp2(st)); l_lane +=
            auto qksm = [&](int kt, const unsigned short* kb) {
                f32x16 st = {};
                #pragma unroll
                for (int s = 0; s < 4; ++s) {
                    bf16x8 kf = ld_frag((const char*)kb + kaddr[s]);
                    st = mfma32(kf, __builtin_bit_cast(bf16x8, qb[s]), st);
                }
                float pex[16];
                if (kt >= tdiag) {            // causal mask (2 diagonal k-tiles)
                    const int qth = (i0 + wq * 32 + l31) - (kt * 64 + wk * 32 + 8 * h);
                    #pragma unroll
                    for (int rr = 0; rr < 16; ++rr) {
                        const int K0 = (rr & 7) | ((rr & 8) << 1);
                        pex[rr] = fexp2((K0 > qth) ? -3.0e38f : st[rr]);
                    }
                } else {
                    #pragma unroll
                    for (int rr = 0; rr < 16; ++rr)
                        pex[rr] = fexp2(st[rr]);
                }
                // reg order == PV A-layout k order (K row permutation):
                // A slice t = words u[4t..4t+3], kpos = wk*32 + 16t + 8h + (0..7)
                #pragma unroll
                for (int g = 0; g < 4; ++g) {
                    u[2 * g]     = pk2bf(pex[4 * g],     pex[4 * g + 1]);
                    u[2 * g + 1] = pk2bf(pex[4 * g + 2], pex[4 * g + 3]);
                }
                // per-lane row-sum partial (tree)
                float s0 = (pex[0] + pex[1]) + (pex[2] + pex[3]);
                float s1 = (pex[4] + pex[5]) + (pex[6] + pex[7]);
                float s2 = (pex[8] + pex[9]) + (pex[10] + pex[11]);
                float s3 = (pex[12] + pex[13]) + (pex[14] + pex[15]);
                l_lane += (s0 + s1) + (s2 + s3);
            };

            // ---- peel: stage lead of 2, QK+softmax of kt0 (no PV yet) ----
            const int last0 = (kt1 - 1 < kt0 + 2) ? kt1 - 1 : kt0 + 2;
            dma(kt0);
            if (last0 > kt0)     dma(kt0 + 1);
            if (last0 > kt0 + 1) dma(kt0 + 2);
            {
                const int inf = last0 - kt0;
                if (inf == 2)      asm volatile("s_waitcnt vmcnt(4)" ::: "memory");
                else if (inf == 1) asm volatile("s_waitcnt vmcnt(2)" ::: "memory");
                else               asm volatile("s_waitcnt vmcnt(0)" ::: "memory");
            }
            __builtin_amdgcn_sched_barrier(0);
            __builtin_amdgcn_s_barrier();          // kt0 staged data visible to all
            __builtin_amdgcn_sched_barrier(0);
            qksm(kt0, &smem[(kt0 & 3) * 4096]);

            // ---- steady state: PV(kt-1) || QK(kt), lead-2 circular staging ----
            for (int kt = kt0 + 1; kt < kt1; ++kt) {
                __builtin_amdgcn_s_barrier();      // all waves done reading slot (kt+2)&3's old tiles
                __builtin_amdgcn_sched_barrier(0);
                if (kt + 2 < kt1) dma(kt + 2);
                {
                    const int last = (kt1 - 1 < kt + 2) ? kt1 - 1 : kt + 2;
                    const int inf  = last - kt;
                    if (inf == 2)      asm volatile("s_waitcnt vmcnt(4)" ::: "memory");
                    else if (inf == 1) asm volatile("s_waitcnt vmcnt(2)" ::: "memory");
                    else               asm volatile("s_waitcnt vmcnt(0)" ::: "memory");
                }
                __builtin_amdgcn_sched_barrier(0);
                __builtin_amdgcn_s_barrier();      // kt staged data visible to all
                __builtin_amdgcn_sched_barrier(0);
                pv(&smem[16384 + ((kt - 1) & 3) * 4096]);   // independent of QK(kt)
                qksm(kt, &smem[(kt & 3) * 4096]);
            }
            // ---- drain: last tile's PV ----
            pv(&smem[16384 + ((kt1 - 1) & 3) * 4096]);
        }

        // ---- cross-wk reduction through the freed k-tile LDS (once per item) ----
        __syncthreads();                           // everyone done with smem
        float* red  = reinterpret_cast<float*>(&smem[0]);   // 8192 f32 = 32 KB
        float* lsum = red + 8192;                           // 512 f32 (2 KB)
        if (wk == 1) {
            #pragma unroll
            for (int rr = 0; rr < 16; ++rr) {
                const int qrow = (rr & 3) + 8 * (rr >> 2) + 4 * h;   // 0..31
                #pragma unroll
                for (int dvt = 0; dvt < 2; ++dvt)
                    red[wq * 2048 + qrow * 64 + dvt * 32 + l31] = o_acc[dvt][rr];
            }
        }
        lsum[(wk * 2 + h) * 128 + wq * 32 + l31] = l_lane;
        __syncthreads();
        if (wk == 0) {
            if (half < 0) {
                // final: normalize and write O directly
                float* obase = O + ((size_t)b * N_SEQ + i0 + wq * 32) * DIM;
                #pragma unroll
                for (int rr = 0; rr < 16; ++rr) {
                    const int qrow = (rr & 3) + 8 * (rr >> 2) + 4 * h;
                    const int qi   = wq * 32 + qrow;
                    const float lt = (lsum[qi] + lsum[128 + qi])
                                   + (lsum[256 + qi] + lsum[384 + qi]);
                    const float inv = 1.0f / lt;
                    #pragma unroll
                    for (int dvt = 0; dvt < 2; ++dvt) {
                        const float val = o_acc[dvt][rr]
                            + red[wq * 2048 + qrow * 64 + dvt * 32 + l31];
                        obase[qrow * DIM + dvt * 32 + l31] = val * inv;
                    }
                }
            } else {
                // raw additive partial -> workspace (deep tiles 16..31)
                float* po = wsO + (((size_t)(b * 16 + (tt - 16)) * 2 + half) * 8192);
                float* pl = wsL + (((size_t)(b * 16 + (tt - 16)) * 2 + half) * 128);
                #pragma unroll
                for (int rr = 0; rr < 16; ++rr) {
                    const int qrow = (rr & 3) + 8 * (rr >> 2) + 4 * h;
                    const int qi   = wq * 32 + qrow;
                    const float lt = (lsum[qi] + lsum[128 + qi])
                                   + (lsum[256 + qi] + lsum[384 + qi]);
                    #pragma unroll
                    for (int dvt = 0; dvt < 2; ++dvt)
                        po[qi * 64 + dvt * 32 + l31] = o_acc[dvt][rr]
                            + red[wq * 2048 + qrow * 64 + dvt * 32 + l31];
                    if (l31 == 0) pl[qi] = lt;
                }
            }
        }
        // next item's top-of-loop __syncthreads() protects smem reuse
    }
}

// ---- combine split-K partials for deep tiles 16..31 (128 rows each) ----
__global__ __launch_bounds__(256)
void norm_out(const float* __restrict__ wsO, const float* __restrict__ wsL,
              float* __restrict__ O) {
    const int t = 16 + blockIdx.x, b = blockIdx.y;
    const int row = threadIdx.x >> 1;            // 0..127
    const int c0  = (threadIdx.x & 1) * 32;      // 0,32
    const size_t base = (size_t)(b * 16 + (t - 16)) * 2;
    const float* p0 = wsO + base * 8192 + row * 64 + c0;
    const float* p1 = p0 + 8192;
    const float* l  = wsL + base * 128;
    const float inv = 1.0f / (l[row] + l[128 + row]);
    float* o = O + ((size_t)b * N_SEQ + t * 128 + row) * 64 + c0;
    #pragma unroll
    for (int i = 0; i < 32; i += 4) {
        f32x4 a = *reinterpret_cast<const f32x4*>(p0 + i);
        f32x4 c = *reinterpret_cast<const f32x4*>(p1 + i);
        f32x4 v = (a + c) * inv;
        *reinterpret_cast<f32x4*>(o + i) = v;
    }
}

extern "C" void kernel_launch(void* const* d_in, const int* in_sizes, int n_in,
                              void* d_out, int out_size, void* d_ws, size_t ws_size,
                              hipStream_t stream) {
    const float* q = (const float*)d_in[0];
    const float* k = (const float*)d_in[1];
    const float* v = (const float*)d_in[2];
    // d_in[3] = causal mask, analytic (tril) -- not read.
    float* out = (float*)d_out;

    unsigned short* wsK = (unsigned short*)d_ws;
    unsigned short* wsV = wsK + (size_t)16 * 64 * 4096;        // 8 MB each
    float* wsO = (float*)(wsV + (size_t)16 * 64 * 4096);       // 16.8 MB
    float* wsL = wsO + (size_t)16 * 16 * 2 * 8192;             // 0.26 MB

    prep_kv<<<dim3(64, 16, 2), dim3(256), 0, stream>>>(k, v, wsK, wsV);
    attn_fwd<<<dim3(512), dim3(512), 0, stream>>>(q, wsK, wsV, out, wsO, wsL);
    norm_out<<<dim3(16, 16), dim3(256), 0, stream>>>(wsO, wsL, out);
}